// Round 12
// baseline (90.874 us; speedup 1.0000x reference)
//
#include <hip/hip_runtime.h>
#include <math.h>

#define FBINS 2112            // 33 * 64 bins; slot = w'*64 + p(h), p(h)=(h&7)*8+(h>>3)
#define CSC 66                // LDS column stride in cplx; 66 % 16 == 2

// Packed complex: (re, im) in a VGPR-pair -> v_pk_*_f32 dual-issue fp32.
typedef float cplx __attribute__((ext_vector_type(2)));
typedef __fp16 half2v __attribute__((ext_vector_type(2)));
#define MK2(a,b) (cplx){(float)(a), (float)(b)}

__device__ __forceinline__ cplx shufxy(cplx a){ return __builtin_shufflevector(a, a, 1, 0); }
template<int S> __device__ __forceinline__ cplx imul(cplx a){   // (i*S) * a
    return (S > 0) ? shufxy(a) * MK2(-1.f, 1.f) : shufxy(a) * MK2(1.f, -1.f);
}
// Table stores W = exp(+2*pi*i*m/64). S=+1: a*W ; S=-1: a*conj(W).
template<int S> __device__ __forceinline__ cplx cmul_tw(cplx a, cplx w){
    cplx ws = shufxy(w);
    return (S > 0) ? a.x*w + a.y*(ws*MK2(-1.f, 1.f))
                   : a.x*(w*MK2(1.f, -1.f)) + a.y*ws;
}

__device__ __forceinline__ unsigned pack16(float a, float b){
    half2v h = __builtin_amdgcn_cvt_pkrtz(a, b);
    return __builtin_bit_cast(unsigned, h);
}
__device__ __forceinline__ half2v h2(unsigned u){ return __builtin_bit_cast(half2v, u); }
__device__ __forceinline__ float fdot2(half2v a, half2v b, float c){
#if __has_builtin(__builtin_amdgcn_fdot2)
    return __builtin_amdgcn_fdot2(a, b, c, false);
#else
    return c + (float)a.x*(float)b.x + (float)a.y*(float)b.y;
#endif
}

// Compile-time twiddles: TWC[j*7+k] = exp(+2*pi*i * j*(k+1) / 64), j=0..7,k=0..6
__device__ __constant__ float TWC[112] = {
  1.f,0.f, 1.f,0.f, 1.f,0.f, 1.f,0.f, 1.f,0.f, 1.f,0.f, 1.f,0.f,
  0.9951847267f,0.0980171403f, 0.9807852804f,0.1950903220f, 0.9569403357f,0.2902846773f,
  0.9238795325f,0.3826834324f, 0.8819212643f,0.4713967368f, 0.8314696123f,0.5555702330f,
  0.7730104534f,0.6343932842f,
  0.9807852804f,0.1950903220f, 0.9238795325f,0.3826834324f, 0.8314696123f,0.5555702330f,
  0.7071067812f,0.7071067812f, 0.5555702330f,0.8314696123f, 0.3826834324f,0.9238795325f,
  0.1950903220f,0.9807852804f,
  0.9569403357f,0.2902846773f, 0.8314696123f,0.5555702330f, 0.6343932842f,0.7730104534f,
  0.3826834324f,0.9238795325f, 0.0980171403f,0.9951847267f, -0.1950903220f,0.9807852804f,
  -0.4713967368f,0.8819212643f,
  0.9238795325f,0.3826834324f, 0.7071067812f,0.7071067812f, 0.3826834324f,0.9238795325f,
  0.f,1.f, -0.3826834324f,0.9238795325f, -0.7071067812f,0.7071067812f,
  -0.9238795325f,0.3826834324f,
  0.8819212643f,0.4713967368f, 0.5555702330f,0.8314696123f, 0.0980171403f,0.9951847267f,
  -0.3826834324f,0.9238795325f, -0.7730104534f,0.6343932842f, -0.9807852804f,0.1950903220f,
  -0.9569403357f,-0.2902846773f,
  0.8314696123f,0.5555702330f, 0.3826834324f,0.9238795325f, -0.1950903220f,0.9807852804f,
  -0.7071067812f,0.7071067812f, -0.9807852804f,0.1950903220f, -0.9238795325f,-0.3826834324f,
  -0.5555702330f,-0.8314696123f,
  0.7730104534f,0.6343932842f, 0.1950903220f,0.9807852804f, -0.4713967368f,0.8819212643f,
  -0.9238795325f,0.3826834324f, -0.9569403357f,-0.2902846773f, -0.5555702330f,-0.8314696123f,
  0.0980171403f,-0.9951847267f
};
__device__ __forceinline__ void load_tw(int j, cplx wj[7]){
    #pragma unroll
    for (int k=0;k<7;++k) wj[k] = MK2(TWC[(j*7+k)*2], TWC[(j*7+k)*2+1]);
}

// Hardcoded 8-point DFT: X[k] = sum_n v[n] * w8^(n*k), w8 = exp(i*S*pi/4).
template<int S>
__device__ __forceinline__ void dft8(cplx v[8]) {
    const float C = 0.70710678118654752440f;
    cplx t0=v[0]+v[4], t4=v[0]-v[4];
    cplx t1=v[1]+v[5], t5=v[1]-v[5];
    cplx t2=v[2]+v[6], t6=v[2]-v[6];
    cplx t3=v[3]+v[7], t7=v[3]-v[7];
    cplx u0=t0+t2, u2=t0-t2;
    cplx u1=t1+t3, u3=t1-t3;
    v[0]=u0+u1; v[4]=u0-u1;
    cplx m3=imul<S>(u3);
    v[2]=u2+m3; v[6]=u2-m3;
    cplx z0=t4;
    cplx z1 = C*(t5 + imul<S>(t5));
    cplx z2 = imul<S>(t6);
    cplx z3 = C*(imul<S>(t7) - t7);
    cplx w0=z0+z2, w2=z0-z2;
    cplx w1=z1+z3, w3=z1-z3;
    v[1]=w0+w1; v[5]=w0-w1;
    cplx mb=imul<S>(w3);
    v[3]=w2+mb; v[7]=w2-mb;
}

// Cooperative 64-point DFT among 8 same-wave lanes. Exchange slots precomputed
// by the caller: wa[k] = base + 8j + (k^j), ra[n] = base + 8n + (j^n) — shared
// by both fft64 calls (same base). Same-wave lockstep => no barrier.
template<int S>
__device__ __forceinline__ void fft64_from_regs(
    cplx v[8], cplx* __restrict__ mem, const int wa[8], const int ra[8],
    const cplx wj[7])
{
    dft8<S>(v);                       // A[j][k1]
    #pragma unroll
    for (int k=1;k<8;++k) v[k] = cmul_tw<S>(v[k], wj[k-1]);  // * w64^(S*j*k1)
    #pragma unroll
    for (int k=0;k<8;++k) mem[wa[k]] = v[k];
    #pragma unroll
    for (int n=0;n<8;++n) v[n] = mem[ra[n]];
    dft8<S>(v);                       // X[j + 8*k2]
}

// Fused forward rfft2: blocks 0..95 -> x planes (dual-form store),
// blocks 96..1631 -> y planes (plain store). Slot = w'*64 + p(h).
// X dual form: cols 0..31: Xa=(re,im), Xb=(-im,re);
//              col 32:     Xa=(im,-re), Xb=(re,im)   [i pre-folded].
__global__ __launch_bounds__(256) void fwd_fft_kernel(
    const float* __restrict__ x, const float* __restrict__ y,
    unsigned* __restrict__ Xa, unsigned* __restrict__ Xb,
    unsigned* __restrict__ Yh, float* __restrict__ pn)
{
    __shared__ __align__(16) cplx CL[2176];
    __shared__ float red[4];
    const int tid = threadIdx.x, G = tid>>3, j = tid&7;
    const int blk = blockIdx.x;
    const bool isX = blk < 96;

    cplx wj[7]; load_tw(j, wj);
    int wa[8], ra[8];
    {
        int base = CSC*G;
        #pragma unroll
        for (int k=0;k<8;++k) wa[k] = base + 8*j + (k^j);
        #pragma unroll
        for (int k=0;k<8;++k) ra[k] = base + 8*k + (j^k);
    }

    const float* img = (isX ? x + (size_t)blk * 4096
                            : y + (size_t)(blk - 96) * 4096);

    // row pass: pack rows (G, G+32): z[w] = row_G[w] + i*row_{G+32}[w].
    {
        cplx v[8];
        float ns = 0.f;
        #pragma unroll
        for (int nn=0;nn<8;++nn){ int w=8*nn+j;
            float a = img[64*G + w], c = img[64*(G+32) + w];
            v[nn] = MK2(a, c);
            ns = fmaf(a, a, ns); ns = fmaf(c, c, ns); }
        #pragma unroll
        for (int off = 32; off; off >>= 1) ns += __shfl_xor(ns, off);
        if ((tid & 63) == 0) red[tid >> 6] = ns;
        fft64_from_regs<-1>(v, CL, wa, ra, wj);
        int base = CSC*G;
        #pragma unroll
        for (int k=0;k<8;++k) CL[base + j + 8*k] = v[k];
    }
    __syncthreads();

    // column pass: group 0 handles packed columns (0,32); group G -> column G.
    {
        cplx v[8];
        if (G == 0) {
            #pragma unroll
            for (int nn=0;nn<8;++nn){
                int r=8*nn+j, p=r&31, hi=r>>5;
                cplx a0  = CL[CSC*p + 0];
                cplx a32 = CL[CSC*p + 32];
                v[nn] = hi ? MK2(a0.y, a32.y) : MK2(a0.x, a32.x);
            }
        } else {
            const int c = G;
            #pragma unroll
            for (int nn=0;nn<8;++nn){
                int r=8*nn+j, p=r&31, hi=r>>5;
                cplx A  = CL[CSC*p + c];
                cplx Bm = CL[CSC*p + 64 - c];
                if (!hi) v[nn] = 0.5f*(A + Bm*MK2(1.f,-1.f));
                else     v[nn] = 0.5f*(shufxy(A)*MK2(1.f,-1.f) + shufxy(Bm));
            }
        }
        __syncthreads();              // row-pass data fully consumed into regs
        fft64_from_regs<-1>(v, CL, wa, ra, wj);
        int base = CSC*G;
        #pragma unroll
        for (int k=0;k<8;++k) CL[base + j + 8*k] = v[k];
    }
    __syncthreads();

    // unpack packed column 0 -> true columns 0 and 32; store fp16 at p(h).
    for (int i = tid; i < FBINS; i += 256) {
        int wp = i>>6, h = i&63;
        cplx r;
        if (wp == 0) {
            int h2i = (64-h)&63;
            cplx av = CL[h], bb = CL[h2i];
            r = 0.5f*(av + bb*MK2(1.f,-1.f));
        } else if (wp == 32) {
            int h2i = (64-h)&63;
            cplx av = CL[h], bb = CL[h2i];
            r = 0.5f*(shufxy(av)*MK2(1.f,-1.f) + shufxy(bb));
        } else {
            r = CL[CSC*wp + h];
        }
        int slot = (wp << 6) | ((h & 7) << 3) | (h >> 3);
        if (isX) {
            size_t o = (size_t)blk * FBINS + slot;
            if (wp == 32) { Xa[o] = pack16(r.y, -r.x); Xb[o] = pack16(r.x, r.y); }
            else          { Xa[o] = pack16(r.x, r.y);  Xb[o] = pack16(-r.y, r.x); }
        } else {
            Yh[(size_t)(blk - 96) * FBINS + slot] = pack16(r.x, r.y);
        }
    }
    if (tid == 0) pn[blk] = red[0] + red[1] + red[2] + red[3];
}

// One block per (b,n) pair, XCD-tiled: XCD x owns n in [64x, 64x+64).
// Step A (conj(X)*Y) fused straight into step-B registers — no LDS staging,
// no swap VALU (dual-X), uniform col-32 merge (i pre-folded into X store).
__global__ __launch_bounds__(256) void corr_kernel(
    const unsigned* __restrict__ Xa, const unsigned* __restrict__ Xb,
    const unsigned* __restrict__ Yh,
    const float* __restrict__ px, const float* __restrict__ py,
    float* __restrict__ out)
{
    __shared__ __align__(16) cplx CL[2176];
    __shared__ float red[4];
    const int tid = threadIdx.x, G = tid>>3, j = tid&7;

    const int blk = blockIdx.x;
    const int xcd = blk & 7, idx = blk >> 3;
    const int n = xcd*64 + (idx & 63);
    const int b = idx >> 6;

    // norm factor; 1/4096 IFFT normalization folded in here.
    const float x2 = px[3*b] + px[3*b+1] + px[3*b+2];
    const float y2 = py[3*n] + py[3*n+1] + py[3*n+2];
    const float dinv = rsqrtf(x2 * y2) * (1.0f/4096.0f);

    int wa[8], ra[8];
    {
        int base = CSC*G;
        #pragma unroll
        for (int k=0;k<8;++k) wa[k] = base + 8*j + (k^j);
        #pragma unroll
        for (int k=0;k<8;++k) ra[k] = base + 8*k + (j^k);
    }

    // ---- step A fused: v[nn] = sum_c conj(X)*Y at (col G, row 8nn+j).
    const uint4* pXa = (const uint4*)Xa + (size_t)b * 3 * 528;
    const uint4* pXb = (const uint4*)Xb + (size_t)b * 3 * 528;
    const uint4* pY  = (const uint4*)Yh + (size_t)n * 3 * 528;
    cplx v[8];
    {
        float r[8], s[8];
        #pragma unroll
        for (int k=0;k<8;++k){ r[k]=0.f; s[k]=0.f; }
        const int off = 16*G + 2*j;
        #pragma unroll
        for (int ch = 0; ch < 3; ++ch) {
            uint4 a0 = pXa[ch*528 + off], a1 = pXa[ch*528 + off + 1];
            uint4 b0 = pXb[ch*528 + off], b1 = pXb[ch*528 + off + 1];
            uint4 y0 = pY [ch*528 + off], y1 = pY [ch*528 + off + 1];
            r[0]=fdot2(h2(a0.x),h2(y0.x),r[0]); s[0]=fdot2(h2(b0.x),h2(y0.x),s[0]);
            r[1]=fdot2(h2(a0.y),h2(y0.y),r[1]); s[1]=fdot2(h2(b0.y),h2(y0.y),s[1]);
            r[2]=fdot2(h2(a0.z),h2(y0.z),r[2]); s[2]=fdot2(h2(b0.z),h2(y0.z),s[2]);
            r[3]=fdot2(h2(a0.w),h2(y0.w),r[3]); s[3]=fdot2(h2(b0.w),h2(y0.w),s[3]);
            r[4]=fdot2(h2(a1.x),h2(y1.x),r[4]); s[4]=fdot2(h2(b1.x),h2(y1.x),s[4]);
            r[5]=fdot2(h2(a1.y),h2(y1.y),r[5]); s[5]=fdot2(h2(b1.y),h2(y1.y),s[5]);
            r[6]=fdot2(h2(a1.z),h2(y1.z),r[6]); s[6]=fdot2(h2(b1.z),h2(y1.z),s[6]);
            r[7]=fdot2(h2(a1.w),h2(y1.w),r[7]); s[7]=fdot2(h2(b1.w),h2(y1.w),s[7]);
        }
        if (G == 0) {   // col-32 merge: i pre-folded into Xa/Xb at store time
            const int off2 = 512 + 2*j;
            #pragma unroll
            for (int ch = 0; ch < 3; ++ch) {
                uint4 a0 = pXa[ch*528 + off2], a1 = pXa[ch*528 + off2 + 1];
                uint4 b0 = pXb[ch*528 + off2], b1 = pXb[ch*528 + off2 + 1];
                uint4 y0 = pY [ch*528 + off2], y1 = pY [ch*528 + off2 + 1];
                r[0]=fdot2(h2(a0.x),h2(y0.x),r[0]); s[0]=fdot2(h2(b0.x),h2(y0.x),s[0]);
                r[1]=fdot2(h2(a0.y),h2(y0.y),r[1]); s[1]=fdot2(h2(b0.y),h2(y0.y),s[1]);
                r[2]=fdot2(h2(a0.z),h2(y0.z),r[2]); s[2]=fdot2(h2(b0.z),h2(y0.z),s[2]);
                r[3]=fdot2(h2(a0.w),h2(y0.w),r[3]); s[3]=fdot2(h2(b0.w),h2(y0.w),s[3]);
                r[4]=fdot2(h2(a1.x),h2(y1.x),r[4]); s[4]=fdot2(h2(b1.x),h2(y1.x),s[4]);
                r[5]=fdot2(h2(a1.y),h2(y1.y),r[5]); s[5]=fdot2(h2(b1.y),h2(y1.y),s[5]);
                r[6]=fdot2(h2(a1.z),h2(y1.z),r[6]); s[6]=fdot2(h2(b1.z),h2(y1.z),s[6]);
                r[7]=fdot2(h2(a1.w),h2(y1.w),r[7]); s[7]=fdot2(h2(b1.w),h2(y1.w),s[7]);
            }
        }
        #pragma unroll
        for (int k=0;k<8;++k) v[k] = MK2(r[k], s[k]);
    }

    cplx wj[7]; load_tw(j, wj);

    // ---- step B: IFFT along h (registers in, LDS out with row-pair remap
    // p(h) = 2*(h&31) + (h>>5) so step C reads b128 row pairs).
    fft64_from_regs<1>(v, CL, wa, ra, wj);
    #pragma unroll
    for (int k=0;k<4;++k)
        *(float4*)&CL[CSC*G + 2*(j+8*k)] =
            make_float4(v[k].x, v[k].y, v[k+4].x, v[k+4].y);
    __syncthreads();
    // packed col 0 holds (c0[h], c32[h]) real pairs; cols 1..31 complex,
    // rows h, h+32 adjacent (float4 per pair).

    // ---- step C: IFFT along w, rows packed pairwise (r1=G, r2=G+32).
    float m = -3.4e38f;
    {
        if (j == 0) {
            float4 f = *(float4*)&CL[2*G];            // packed col 0
            v[0] = MK2(f.x, f.z);                     // w=0: c0 pair
            v[4] = MK2(f.y, f.w);                     // w=32: c32 pair
        } else {
            float4 f = *(float4*)&CL[CSC*j + 2*G];
            v[0] = MK2(f.x,f.y) + imul<1>(MK2(f.z,f.w));
            float4 g2 = *(float4*)&CL[CSC*(32-j) + 2*G];
            v[4] = MK2(g2.x,g2.y)*MK2(1.f,-1.f) + shufxy(MK2(g2.z,g2.w));
        }
        #pragma unroll
        for (int nn=1;nn<4;++nn){                     // w = 8..31
            int w = 8*nn + j;
            float4 f = *(float4*)&CL[CSC*w + 2*G];
            v[nn] = MK2(f.x,f.y) + imul<1>(MK2(f.z,f.w));
        }
        #pragma unroll
        for (int nn=5;nn<8;++nn){                     // w = 40..63 (conj)
            int w2 = 64 - (8*nn + j);
            float4 f = *(float4*)&CL[CSC*w2 + 2*G];
            v[nn] = MK2(f.x,f.y)*MK2(1.f,-1.f) + shufxy(MK2(f.z,f.w));
        }
        __syncthreads();              // all rows consumed; CL becomes scratch
        fft64_from_regs<1>(v, CL, wa, ra, wj);
        #pragma unroll
        for (int k=0;k<8;++k) m = fmaxf(m, fmaxf(v[k].x, v[k].y));
    }
    #pragma unroll
    for (int off = 32; off; off >>= 1) m = fmaxf(m, __shfl_xor(m, off));
    if ((tid & 63) == 0) red[tid >> 6] = m;
    __syncthreads();
    if (tid == 0) {
        float mm = fmaxf(fmaxf(red[0], red[1]), fmaxf(red[2], red[3]));
        out[b*512 + n] = mm * dinv;
    }
}

extern "C" void kernel_launch(void* const* d_in, const int* in_sizes, int n_in,
                              void* d_out, int out_size, void* d_ws, size_t ws_size,
                              hipStream_t stream) {
    const float* x = (const float*)d_in[0];   // (32,3,64,64)
    const float* y = (const float*)d_in[1];   // (512,3,64,64)
    float* out = (float*)d_out;               // (32,512)

    // workspace: Xa[96*2112] | Xb[96*2112] | Yh[1536*2112] u32 | pn[1632]
    unsigned* Xa = (unsigned*)d_ws;
    unsigned* Xb = Xa + 96 * FBINS;
    unsigned* Yh = Xb + 96 * FBINS;
    float* pn = (float*)(Yh + 1536 * FBINS);  // px = pn[0..95], py = pn[96..]
    float* px = pn;
    float* py = pn + 96;

    fwd_fft_kernel<<<1632, 256, 0, stream>>>(x, y, Xa, Xb, Yh, pn);
    corr_kernel<<<16384, 256, 0, stream>>>(Xa, Xb, Yh, px, py, out);
}

// Round 13
// 79.314 us; speedup vs baseline: 1.1458x; 1.1458x over previous
//
#include <hip/hip_runtime.h>
#include <math.h>

#define FBINS 2112            // 33 * 64 bins; slot = w'*64 + p(h), p(h)=(h&7)*8+(h>>3)
#define CSC 66                // LDS column stride in cplx; 66 % 16 == 2

// Packed complex: (re, im) in a VGPR-pair -> v_pk_*_f32 dual-issue fp32.
typedef float cplx __attribute__((ext_vector_type(2)));
typedef __fp16 half2v __attribute__((ext_vector_type(2)));
#define MK2(a,b) (cplx){(float)(a), (float)(b)}

__device__ __forceinline__ cplx shufxy(cplx a){ return __builtin_shufflevector(a, a, 1, 0); }
template<int S> __device__ __forceinline__ cplx imul(cplx a){   // (i*S) * a
    return (S > 0) ? shufxy(a) * MK2(-1.f, 1.f) : shufxy(a) * MK2(1.f, -1.f);
}
// Table stores W = exp(+2*pi*i*m/64). S=+1: a*W ; S=-1: a*conj(W).
template<int S> __device__ __forceinline__ cplx cmul_tw(cplx a, cplx w){
    cplx ws = shufxy(w);
    return (S > 0) ? a.x*w + a.y*(ws*MK2(-1.f, 1.f))
                   : a.x*(w*MK2(1.f, -1.f)) + a.y*ws;
}

__device__ __forceinline__ unsigned pack16(float a, float b){
    half2v h = __builtin_amdgcn_cvt_pkrtz(a, b);
    return __builtin_bit_cast(unsigned, h);
}
__device__ __forceinline__ half2v h2(unsigned u){ return __builtin_bit_cast(half2v, u); }
__device__ __forceinline__ float fdot2(half2v a, half2v b, float c){
#if __has_builtin(__builtin_amdgcn_fdot2)
    return __builtin_amdgcn_fdot2(a, b, c, false);
#else
    return c + (float)a.x*(float)b.x + (float)a.y*(float)b.y;
#endif
}
// re += dot(x, y); im += dot(x, swap16(y)^signhi)  [= conj(x)*y parts]
__device__ __forceinline__ void dotw(unsigned ux, unsigned uy, float& r, float& s){
    unsigned ys = ((uy >> 16) | (uy << 16)) ^ 0x80000000u;   // (im_y, -re_y)
    r = fdot2(h2(ux), h2(uy), r);
    s = fdot2(h2(ux), h2(ys), s);
}
// v += i * (conj(x)*y)   [column-32 merge for the packed column]
__device__ __forceinline__ void dotw_i(unsigned ux, unsigned uy, cplx& v){
    float rr = 0.f, ss = 0.f;
    dotw(ux, uy, rr, ss);
    v += MK2(-ss, rr);
}

// Compile-time twiddles: TWC[j*7+k] = exp(+2*pi*i * j*(k+1) / 64), j=0..7,k=0..6
__device__ __constant__ float TWC[112] = {
  1.f,0.f, 1.f,0.f, 1.f,0.f, 1.f,0.f, 1.f,0.f, 1.f,0.f, 1.f,0.f,
  0.9951847267f,0.0980171403f, 0.9807852804f,0.1950903220f, 0.9569403357f,0.2902846773f,
  0.9238795325f,0.3826834324f, 0.8819212643f,0.4713967368f, 0.8314696123f,0.5555702330f,
  0.7730104534f,0.6343932842f,
  0.9807852804f,0.1950903220f, 0.9238795325f,0.3826834324f, 0.8314696123f,0.5555702330f,
  0.7071067812f,0.7071067812f, 0.5555702330f,0.8314696123f, 0.3826834324f,0.9238795325f,
  0.1950903220f,0.9807852804f,
  0.9569403357f,0.2902846773f, 0.8314696123f,0.5555702330f, 0.6343932842f,0.7730104534f,
  0.3826834324f,0.9238795325f, 0.0980171403f,0.9951847267f, -0.1950903220f,0.9807852804f,
  -0.4713967368f,0.8819212643f,
  0.9238795325f,0.3826834324f, 0.7071067812f,0.7071067812f, 0.3826834324f,0.9238795325f,
  0.f,1.f, -0.3826834324f,0.9238795325f, -0.7071067812f,0.7071067812f,
  -0.9238795325f,0.3826834324f,
  0.8819212643f,0.4713967368f, 0.5555702330f,0.8314696123f, 0.0980171403f,0.9951847267f,
  -0.3826834324f,0.9238795325f, -0.7730104534f,0.6343932842f, -0.9807852804f,0.1950903220f,
  -0.9569403357f,-0.2902846773f,
  0.8314696123f,0.5555702330f, 0.3826834324f,0.9238795325f, -0.1950903220f,0.9807852804f,
  -0.7071067812f,0.7071067812f, -0.9807852804f,0.1950903220f, -0.9238795325f,-0.3826834324f,
  -0.5555702330f,-0.8314696123f,
  0.7730104534f,0.6343932842f, 0.1950903220f,0.9807852804f, -0.4713967368f,0.8819212643f,
  -0.9238795325f,0.3826834324f, -0.9569403357f,-0.2902846773f, -0.5555702330f,-0.8314696123f,
  0.0980171403f,-0.9951847267f
};
__device__ __forceinline__ void load_tw(int j, cplx wj[7]){
    #pragma unroll
    for (int k=0;k<7;++k) wj[k] = MK2(TWC[(j*7+k)*2], TWC[(j*7+k)*2+1]);
}

// Hardcoded 8-point DFT: X[k] = sum_n v[n] * w8^(n*k), w8 = exp(i*S*pi/4).
template<int S>
__device__ __forceinline__ void dft8(cplx v[8]) {
    const float C = 0.70710678118654752440f;
    cplx t0=v[0]+v[4], t4=v[0]-v[4];
    cplx t1=v[1]+v[5], t5=v[1]-v[5];
    cplx t2=v[2]+v[6], t6=v[2]-v[6];
    cplx t3=v[3]+v[7], t7=v[3]-v[7];
    cplx u0=t0+t2, u2=t0-t2;
    cplx u1=t1+t3, u3=t1-t3;
    v[0]=u0+u1; v[4]=u0-u1;
    cplx m3=imul<S>(u3);
    v[2]=u2+m3; v[6]=u2-m3;
    cplx z0=t4;
    cplx z1 = C*(t5 + imul<S>(t5));
    cplx z2 = imul<S>(t6);
    cplx z3 = C*(imul<S>(t7) - t7);
    cplx w0=z0+z2, w2=z0-z2;
    cplx w1=z1+z3, w3=z1-z3;
    v[1]=w0+w1; v[5]=w0-w1;
    cplx mb=imul<S>(w3);
    v[3]=w2+mb; v[7]=w2-mb;
}

// Cooperative 64-point DFT among 8 same-wave lanes. Exchange slots precomputed
// by the caller: wa[k] = base + 8j + (k^j), ra[n] = base + 8n + (j^n) — shared
// by both fft64 calls (same base). Same-wave lockstep => no barrier.
template<int S>
__device__ __forceinline__ void fft64_from_regs(
    cplx v[8], cplx* __restrict__ mem, const int wa[8], const int ra[8],
    const cplx wj[7])
{
    dft8<S>(v);                       // A[j][k1]
    #pragma unroll
    for (int k=1;k<8;++k) v[k] = cmul_tw<S>(v[k], wj[k-1]);  // * w64^(S*j*k1)
    #pragma unroll
    for (int k=0;k<8;++k) mem[wa[k]] = v[k];
    #pragma unroll
    for (int n=0;n<8;++n) v[n] = mem[ra[n]];
    dft8<S>(v);                       // X[j + 8*k2]
}

// Fused forward rfft2: blocks 0..95 -> x planes, 96..1631 -> y planes.
// Output fp16-packed u32 at slot w'*64 + p(h), p(h) = (h&7)*8 + (h>>3).
__global__ __launch_bounds__(256) void fwd_fft_kernel(
    const float* __restrict__ x, const float* __restrict__ y,
    unsigned* __restrict__ Xh, unsigned* __restrict__ Yh,
    float* __restrict__ pn)
{
    __shared__ __align__(16) cplx CL[2176];
    __shared__ float red[4];
    const int tid = threadIdx.x, G = tid>>3, j = tid&7;
    const int blk = blockIdx.x;
    const bool isX = blk < 96;

    cplx wj[7]; load_tw(j, wj);
    int wa[8], ra[8];
    {
        int base = CSC*G;
        #pragma unroll
        for (int k=0;k<8;++k) wa[k] = base + 8*j + (k^j);
        #pragma unroll
        for (int k=0;k<8;++k) ra[k] = base + 8*k + (j^k);
    }

    const float* img = (isX ? x + (size_t)blk * 4096
                            : y + (size_t)(blk - 96) * 4096);
    unsigned* o = (isX ? Xh + (size_t)blk * FBINS
                       : Yh + (size_t)(blk - 96) * FBINS);

    // row pass: pack rows (G, G+32): z[w] = row_G[w] + i*row_{G+32}[w].
    {
        cplx v[8];
        float ns = 0.f;
        #pragma unroll
        for (int nn=0;nn<8;++nn){ int w=8*nn+j;
            float a = img[64*G + w], c = img[64*(G+32) + w];
            v[nn] = MK2(a, c);
            ns = fmaf(a, a, ns); ns = fmaf(c, c, ns); }
        #pragma unroll
        for (int off = 32; off; off >>= 1) ns += __shfl_xor(ns, off);
        if ((tid & 63) == 0) red[tid >> 6] = ns;
        fft64_from_regs<-1>(v, CL, wa, ra, wj);
        int base = CSC*G;
        #pragma unroll
        for (int k=0;k<8;++k) CL[base + j + 8*k] = v[k];
    }
    __syncthreads();

    // column pass: group 0 handles packed columns (0,32); group G -> column G.
    {
        cplx v[8];
        if (G == 0) {
            #pragma unroll
            for (int nn=0;nn<8;++nn){
                int r=8*nn+j, p=r&31, hi=r>>5;
                cplx a0  = CL[CSC*p + 0];
                cplx a32 = CL[CSC*p + 32];
                v[nn] = hi ? MK2(a0.y, a32.y) : MK2(a0.x, a32.x);
            }
        } else {
            const int c = G;
            #pragma unroll
            for (int nn=0;nn<8;++nn){
                int r=8*nn+j, p=r&31, hi=r>>5;
                cplx A  = CL[CSC*p + c];
                cplx Bm = CL[CSC*p + 64 - c];
                if (!hi) v[nn] = 0.5f*(A + Bm*MK2(1.f,-1.f));
                else     v[nn] = 0.5f*(shufxy(A)*MK2(1.f,-1.f) + shufxy(Bm));
            }
        }
        __syncthreads();              // row-pass data fully consumed into regs
        fft64_from_regs<-1>(v, CL, wa, ra, wj);
        int base = CSC*G;
        #pragma unroll
        for (int k=0;k<8;++k) CL[base + j + 8*k] = v[k];
    }
    __syncthreads();

    // unpack packed column 0 -> true columns 0 and 32; store fp16 at p(h).
    for (int i = tid; i < FBINS; i += 256) {
        int wp = i>>6, h = i&63;
        cplx r;
        if (wp == 0) {
            int h2i = (64-h)&63;
            cplx av = CL[h], bb = CL[h2i];
            r = 0.5f*(av + bb*MK2(1.f,-1.f));
        } else if (wp == 32) {
            int h2i = (64-h)&63;
            cplx av = CL[h], bb = CL[h2i];
            r = 0.5f*(shufxy(av)*MK2(1.f,-1.f) + shufxy(bb));
        } else {
            r = CL[CSC*wp + h];
        }
        int slot = (wp << 6) | ((h & 7) << 3) | (h >> 3);
        o[slot] = pack16(r.x, r.y);
    }
    if (tid == 0) pn[blk] = red[0] + red[1] + red[2] + red[3];
}

// One block per (b,n) pair, XCD-tiled: XCD x owns n in [64x, 64x+64).
// Step A (conj(X)*Y) fused straight into step-B registers — no LDS staging.
__global__ __launch_bounds__(256) void corr_kernel(
    const unsigned* __restrict__ Xh, const unsigned* __restrict__ Yh,
    const float* __restrict__ px, const float* __restrict__ py,
    float* __restrict__ out)
{
    __shared__ __align__(16) cplx CL[2176];
    __shared__ float red[4];
    const int tid = threadIdx.x, G = tid>>3, j = tid&7;

    const int blk = blockIdx.x;
    const int xcd = blk & 7, idx = blk >> 3;
    const int n = xcd*64 + (idx & 63);
    const int b = idx >> 6;

    // norm factor; 1/4096 IFFT normalization folded in here.
    const float x2 = px[3*b] + px[3*b+1] + px[3*b+2];
    const float y2 = py[3*n] + py[3*n+1] + py[3*n+2];
    const float dinv = rsqrtf(x2 * y2) * (1.0f/4096.0f);

    int wa[8], ra[8];
    {
        int base = CSC*G;
        #pragma unroll
        for (int k=0;k<8;++k) wa[k] = base + 8*j + (k^j);
        #pragma unroll
        for (int k=0;k<8;++k) ra[k] = base + 8*k + (j^k);
    }

    // ---- step A fused: v[nn] = sum_c conj(X)*Y at (col G, row 8nn+j).
    // Fragment layout gives thread (G,j) its 8 rows as 2 uint4 loads/stream.
    const uint4* pX4 = (const uint4*)Xh + (size_t)b * 3 * 528;
    const uint4* pY4 = (const uint4*)Yh + (size_t)n * 3 * 528;
    cplx v[8];
    {
        float r[8], s[8];
        #pragma unroll
        for (int k=0;k<8;++k){ r[k]=0.f; s[k]=0.f; }
        const int off = 16*G + 2*j;
        #pragma unroll
        for (int ch = 0; ch < 3; ++ch) {
            uint4 x0 = pX4[ch*528 + off], x1 = pX4[ch*528 + off + 1];
            uint4 y0 = pY4[ch*528 + off], y1 = pY4[ch*528 + off + 1];
            dotw(x0.x, y0.x, r[0], s[0]);  dotw(x0.y, y0.y, r[1], s[1]);
            dotw(x0.z, y0.z, r[2], s[2]);  dotw(x0.w, y0.w, r[3], s[3]);
            dotw(x1.x, y1.x, r[4], s[4]);  dotw(x1.y, y1.y, r[5], s[5]);
            dotw(x1.z, y1.z, r[6], s[6]);  dotw(x1.w, y1.w, r[7], s[7]);
        }
        #pragma unroll
        for (int k=0;k<8;++k) v[k] = MK2(r[k], s[k]);
    }
    if (G == 0) {   // merge column 32: v += i * (conj(X)*Y)|col32
        const int off = 512 + 2*j;
        #pragma unroll
        for (int ch = 0; ch < 3; ++ch) {
            uint4 x0 = pX4[ch*528 + off], x1 = pX4[ch*528 + off + 1];
            uint4 y0 = pY4[ch*528 + off], y1 = pY4[ch*528 + off + 1];
            dotw_i(x0.x, y0.x, v[0]);  dotw_i(x0.y, y0.y, v[1]);
            dotw_i(x0.z, y0.z, v[2]);  dotw_i(x0.w, y0.w, v[3]);
            dotw_i(x1.x, y1.x, v[4]);  dotw_i(x1.y, y1.y, v[5]);
            dotw_i(x1.z, y1.z, v[6]);  dotw_i(x1.w, y1.w, v[7]);
        }
    }

    cplx wj[7]; load_tw(j, wj);

    // ---- step B: IFFT along h (registers in, LDS out with row-pair remap
    // p(h) = 2*(h&31) + (h>>5) so step C reads b128 row pairs).
    fft64_from_regs<1>(v, CL, wa, ra, wj);
    #pragma unroll
    for (int k=0;k<4;++k)
        *(float4*)&CL[CSC*G + 2*(j+8*k)] =
            make_float4(v[k].x, v[k].y, v[k+4].x, v[k+4].y);
    __syncthreads();
    // packed col 0 holds (c0[h], c32[h]) real pairs; cols 1..31 complex,
    // rows h, h+32 adjacent (float4 per pair).

    // ---- step C: IFFT along w, rows packed pairwise (r1=G, r2=G+32).
    float m = -3.4e38f;
    {
        if (j == 0) {
            float4 f = *(float4*)&CL[2*G];            // packed col 0
            v[0] = MK2(f.x, f.z);                     // w=0: c0 pair
            v[4] = MK2(f.y, f.w);                     // w=32: c32 pair
        } else {
            float4 f = *(float4*)&CL[CSC*j + 2*G];
            v[0] = MK2(f.x,f.y) + imul<1>(MK2(f.z,f.w));
            float4 g2 = *(float4*)&CL[CSC*(32-j) + 2*G];
            v[4] = MK2(g2.x,g2.y)*MK2(1.f,-1.f) + shufxy(MK2(g2.z,g2.w));
        }
        #pragma unroll
        for (int nn=1;nn<4;++nn){                     // w = 8..31
            int w = 8*nn + j;
            float4 f = *(float4*)&CL[CSC*w + 2*G];
            v[nn] = MK2(f.x,f.y) + imul<1>(MK2(f.z,f.w));
        }
        #pragma unroll
        for (int nn=5;nn<8;++nn){                     // w = 40..63 (conj)
            int w2 = 64 - (8*nn + j);
            float4 f = *(float4*)&CL[CSC*w2 + 2*G];
            v[nn] = MK2(f.x,f.y)*MK2(1.f,-1.f) + shufxy(MK2(f.z,f.w));
        }
        __syncthreads();              // all rows consumed; CL becomes scratch
        fft64_from_regs<1>(v, CL, wa, ra, wj);
        #pragma unroll
        for (int k=0;k<8;++k) m = fmaxf(m, fmaxf(v[k].x, v[k].y));
    }
    #pragma unroll
    for (int off = 32; off; off >>= 1) m = fmaxf(m, __shfl_xor(m, off));
    if ((tid & 63) == 0) red[tid >> 6] = m;
    __syncthreads();
    if (tid == 0) {
        float mm = fmaxf(fmaxf(red[0], red[1]), fmaxf(red[2], red[3]));
        out[b*512 + n] = mm * dinv;
    }
}

extern "C" void kernel_launch(void* const* d_in, const int* in_sizes, int n_in,
                              void* d_out, int out_size, void* d_ws, size_t ws_size,
                              hipStream_t stream) {
    const float* x = (const float*)d_in[0];   // (32,3,64,64)
    const float* y = (const float*)d_in[1];   // (512,3,64,64)
    float* out = (float*)d_out;               // (32,512)

    // workspace: Xh[96*2112] u32 | Yh[1536*2112] u32 | pn[1632]
    unsigned* Xh = (unsigned*)d_ws;
    unsigned* Yh = Xh + 96 * FBINS;
    float* pn = (float*)(Yh + 1536 * FBINS);  // px = pn[0..95], py = pn[96..]
    float* px = pn;
    float* py = pn + 96;

    fwd_fft_kernel<<<1632, 256, 0, stream>>>(x, y, Xh, Yh, pn);
    corr_kernel<<<16384, 256, 0, stream>>>(Xh, Yh, px, py, out);
}